// Round 1
// baseline (423.299 us; speedup 1.0000x reference)
//
#include <hip/hip_runtime.h>
#include <hip/hip_bf16.h>

#define HID 128

typedef __attribute__((ext_vector_type(8))) short short8;   // 8 x bf16 (4 VGPRs)
typedef __attribute__((ext_vector_type(4))) float f32x4;    // MFMA C/D

static __device__ __forceinline__ short f2bf(float x) {
    __hip_bfloat16 h = __float2bfloat16(x);   // RNE
    return *reinterpret_cast<short*>(&h);
}

// ---------------------------------------------------------------------------
// K1: the two INDEPENDENT 128x128 products in one launch, plus the bias
// chain parallelized over its 128 outputs.
//   blocks 0..127   : P_left  = Wo  @ W_mo      (row b)
//   blocks 128..255 : P_right = Wiv @ Wv        (row b-128)
//   block  256      : cv = 0.5*(Wo@(W_mo@(Wiv@bv + biv) + b_mo) + bo)
// ---------------------------------------------------------------------------
__global__ void prep_products(const float* __restrict__ Wo,
                              const float* __restrict__ W_mo,
                              const float* __restrict__ Wiv,
                              const float* __restrict__ Wv,
                              const float* __restrict__ bv,
                              const float* __restrict__ biv,
                              const float* __restrict__ b_mo,
                              const float* __restrict__ bo,
                              float* __restrict__ Pl,
                              float* __restrict__ Pr,
                              float* __restrict__ cv)
{
    const int j = threadIdx.x;
    const int b = blockIdx.x;
    __shared__ float sh[HID];

    if (b < 256) {
        const float* A = (b < 128) ? Wo   : Wiv;
        const float* B = (b < 128) ? W_mo : Wv;
        float*       C = (b < 128) ? Pl   : Pr;
        const int i = b & 127;
        sh[j] = A[i * HID + j];
        __syncthreads();
        float s = 0.f;
        #pragma unroll 16
        for (int k = 0; k < HID; ++k) s += sh[k] * B[k * HID + j];
        C[i * HID + j] = s;
    } else {
        // bias chain: 3 matvecs, each parallel over the 128 outputs.
        sh[j] = bv[j];
        __syncthreads();
        float t = biv[j];
        #pragma unroll 16
        for (int k = 0; k < HID; ++k) t += Wiv[j * HID + k] * sh[k];
        __syncthreads(); sh[j] = t; __syncthreads();
        t = b_mo[j];
        #pragma unroll 16
        for (int k = 0; k < HID; ++k) t += W_mo[j * HID + k] * sh[k];
        __syncthreads(); sh[j] = t; __syncthreads();
        t = bo[j];
        #pragma unroll 16
        for (int k = 0; k < HID; ++k) t += Wo[j * HID + k] * sh[k];
        cv[j] = 0.5f * t;
    }
}

// ---------------------------------------------------------------------------
// K2: M' = bf16( I + 0.5 * P_left @ P_right )   (row-major [n][k])
// ---------------------------------------------------------------------------
__global__ void prep_final(const float* __restrict__ Pl,
                           const float* __restrict__ Pr,
                           __hip_bfloat16* __restrict__ Mb)
{
    const int i = blockIdx.x, j = threadIdx.x;
    __shared__ float sh[HID];
    sh[j] = Pl[i * HID + j];
    __syncthreads();
    float s = 0.f;
    #pragma unroll 16
    for (int k = 0; k < HID; ++k) s += sh[k] * Pr[k * HID + j];
    Mb[i * HID + j] = __float2bfloat16(((i == j) ? 1.0f : 0.0f) + 0.5f * s);
}

// ---------------------------------------------------------------------------
// Main: out[e][:] = ea[e][:] @ M'^T + cv      (fp32 in/out, bf16 MFMA)
//
// M' is the A-operand (features = M-dim, in registers), edges are the
// B-operand (N-dim, across lanes). C/D layout gives each lane 4 CONTIGUOUS
// floats of one edge row per acc register -> dwordx4 nontemporal stores.
//
// R3 change: grid 1024 -> 2048. rocprof showed Occupancy 31% with all pipes
// idle (MfmaUtil 3.2, VALU 6.8, HBM 27%): the kernel was grid-limited to
// 4 blocks/CU = 16 waves/CU while VGPR=60 (<=64) allows 8 blocks/CU = 32
// waves/CU. __launch_bounds__(256, 8) pins the allocator to <=64 VGPR so
// the full-occupancy budget is guaranteed.
// ---------------------------------------------------------------------------
__global__ __launch_bounds__(256, 8) void edge_gemm(
    const float* __restrict__ ea,
    const __hip_bfloat16* __restrict__ Mb,   // [128][128] bf16: M'[n][k]
    const float* __restrict__ cvec,          // [128] = 0.5*c
    float* __restrict__ out,
    int E, int numTiles)
{
    const int lane  = threadIdx.x & 63;
    const int wv    = threadIdx.x >> 6;
    const int q     = lane >> 4;      // 0..3
    const int c     = lane & 15;      // 0..15
    const int ncol0 = wv * 32;        // this wave's 32 output cols

    // A-frag: lane (q,c) holds M'[ncol0 + nt*16 + c][kk*32 + q*8 .. +7]
    short8 Mfrag[2][4];
    #pragma unroll
    for (int nt = 0; nt < 2; ++nt) {
        const __hip_bfloat16* mp = Mb + (size_t)(ncol0 + nt * 16 + c) * HID + q * 8;
        #pragma unroll
        for (int kk = 0; kk < 4; ++kk)
            Mfrag[nt][kk] = *reinterpret_cast<const short8*>(mp + kk * 32);
    }
    // Bias as accumulator init: acc[nt][r] <-> out col ncol0 + nt*16 + q*4 + r
    f32x4 cvp[2];
    #pragma unroll
    for (int nt = 0; nt < 2; ++nt)
        cvp[nt] = *reinterpret_cast<const f32x4*>(cvec + ncol0 + nt * 16 + q * 4);

    int t = blockIdx.x;
    if (t >= numTiles) return;

    // Preload tile t's edge data (raw fp32; cast to bf16 when consumed).
    float4 raw[8];
    {
        int row = t * 16 + c; if (row > E - 1) row = E - 1;
        const float* ap = ea + (size_t)row * HID + q * 8;
        #pragma unroll
        for (int kk = 0; kk < 4; ++kk) {
            raw[2 * kk]     = *reinterpret_cast<const float4*>(ap + kk * 32);
            raw[2 * kk + 1] = *reinterpret_cast<const float4*>(ap + kk * 32 + 4);
        }
    }

    while (true) {
        const int edge0 = t * 16;
        const int tn    = t + gridDim.x;

        // B-frag: lane (q,c) holds ea[edge0+c][kk*32 + q*8 .. +7] as bf16.
        short8 bfrag[4];
        #pragma unroll
        for (int kk = 0; kk < 4; ++kk) {
            const float4 f0 = raw[2 * kk], f1 = raw[2 * kk + 1];
            short8 v;
            v[0] = f2bf(f0.x); v[1] = f2bf(f0.y); v[2] = f2bf(f0.z); v[3] = f2bf(f0.w);
            v[4] = f2bf(f1.x); v[5] = f2bf(f1.y); v[6] = f2bf(f1.z); v[7] = f2bf(f1.w);
            bfrag[kk] = v;
        }

        // Software prefetch of tile tn (issued BEFORE this tile's stores).
        if (tn < numTiles) {
            int row = tn * 16 + c; if (row > E - 1) row = E - 1;
            const float* ap = ea + (size_t)row * HID + q * 8;
            #pragma unroll
            for (int kk = 0; kk < 4; ++kk) {
                raw[2 * kk]     = *reinterpret_cast<const float4*>(ap + kk * 32);
                raw[2 * kk + 1] = *reinterpret_cast<const float4*>(ap + kk * 32 + 4);
            }
        }

        f32x4 acc[2] = { cvp[0], cvp[1] };
        #pragma unroll
        for (int kk = 0; kk < 4; ++kk) {
            acc[0] = __builtin_amdgcn_mfma_f32_16x16x32_bf16(Mfrag[0][kk], bfrag[kk], acc[0], 0, 0, 0);
            acc[1] = __builtin_amdgcn_mfma_f32_16x16x32_bf16(Mfrag[1][kk], bfrag[kk], acc[1], 0, 0, 0);
        }

        // acc[nt] = out[edge0+c][ncol0 + nt*16 + q*4 .. +3]  — contiguous.
        const int orow = edge0 + c;
        if (orow < E) {
            float* op = out + (size_t)orow * HID + ncol0 + q * 4;
            __builtin_nontemporal_store(acc[0], reinterpret_cast<f32x4*>(op));
            __builtin_nontemporal_store(acc[1], reinterpret_cast<f32x4*>(op + 16));
        }

        if (tn >= numTiles) break;
        t = tn;
    }
}

// ---------------------------------------------------------------------------
// Inputs (setup_inputs order, all float32; edge_index int64 — DEAD):
//  0 edge_attr  1 node_features(DEAD)  2 regime_probs(DEAD)
//  3 Wq 4 bq 5 Wk 6 bk (DEAD: softmax over singleton seq = 1 => att = v2)
//  7 Wv 8 bv  9 W_in[3*128,128] 10 b_in[384] (only value third live)
// 11 W_mo 12 b_mo 13 Wo 14 bo 15 edge_index(DEAD)
// out = ea @ (I + 0.5*Wo@W_mo@Wiv@Wv)^T + 0.5*c
// ---------------------------------------------------------------------------
extern "C" void kernel_launch(void* const* d_in, const int* in_sizes, int n_in,
                              void* d_out, int out_size, void* d_ws, size_t ws_size,
                              hipStream_t stream) {
    const float* Wv   = (const float*)d_in[7];
    const float* bv   = (const float*)d_in[8];
    const float* W_in = (const float*)d_in[9];
    const float* b_in = (const float*)d_in[10];
    const float* W_mo = (const float*)d_in[11];
    const float* b_mo = (const float*)d_in[12];
    const float* Wo   = (const float*)d_in[13];
    const float* bo   = (const float*)d_in[14];
    const float* Wiv  = W_in + 2 * HID * HID;   // value third of packed in-proj
    const float* biv  = b_in + 2 * HID;

    char* ws = (char*)d_ws;
    float*          Pl = (float*)(ws);                    // 64 KB
    float*          Pr = (float*)(ws + 65536);            // 64 KB
    __hip_bfloat16* Mb = (__hip_bfloat16*)(ws + 131072);  // 32 KB
    float*          cv = (float*)(ws + 163840);           // 512 B

    const int E = in_sizes[0] / HID;
    const int numTiles = (E + 15) / 16;
    const int grid = numTiles < 2048 ? numTiles : 2048;   // 8 blocks/CU resident

    prep_products<<<dim3(257), dim3(HID), 0, stream>>>(
        Wo, W_mo, Wiv, Wv, bv, biv, b_mo, bo, Pl, Pr, cv);
    prep_final<<<dim3(HID), dim3(HID), 0, stream>>>(Pl, Pr, Mb);

    edge_gemm<<<dim3(grid), dim3(256), 0, stream>>>(
        (const float*)d_in[0], Mb, cv, (float*)d_out, E, numTiles);
}

// Round 2
// 298.012 us; speedup vs baseline: 1.4204x; 1.4204x over previous
//
#include <hip/hip_runtime.h>
#include <hip/hip_bf16.h>

#define HID 128

typedef __attribute__((ext_vector_type(8))) short short8;   // 8 x bf16 (4 VGPRs)
typedef __attribute__((ext_vector_type(4))) float f32x4;    // MFMA C/D

static __device__ __forceinline__ short f2bf(float x) {
    __hip_bfloat16 h = __float2bfloat16(x);   // RNE
    return *reinterpret_cast<short*>(&h);
}

// ---------------------------------------------------------------------------
// K1: the two INDEPENDENT 128x128 products in one launch, plus the bias
// chain parallelized over its 128 outputs.
//   blocks 0..127   : P_left  = Wo  @ W_mo      (row b)
//   blocks 128..255 : P_right = Wiv @ Wv        (row b-128)
//   block  256      : cv = 0.5*(Wo@(W_mo@(Wiv@bv + biv) + b_mo) + bo)
// ---------------------------------------------------------------------------
__global__ void prep_products(const float* __restrict__ Wo,
                              const float* __restrict__ W_mo,
                              const float* __restrict__ Wiv,
                              const float* __restrict__ Wv,
                              const float* __restrict__ bv,
                              const float* __restrict__ biv,
                              const float* __restrict__ b_mo,
                              const float* __restrict__ bo,
                              float* __restrict__ Pl,
                              float* __restrict__ Pr,
                              float* __restrict__ cv)
{
    const int j = threadIdx.x;
    const int b = blockIdx.x;
    __shared__ float sh[HID];

    if (b < 256) {
        const float* A = (b < 128) ? Wo   : Wiv;
        const float* B = (b < 128) ? W_mo : Wv;
        float*       C = (b < 128) ? Pl   : Pr;
        const int i = b & 127;
        sh[j] = A[i * HID + j];
        __syncthreads();
        float s = 0.f;
        #pragma unroll 16
        for (int k = 0; k < HID; ++k) s += sh[k] * B[k * HID + j];
        C[i * HID + j] = s;
    } else {
        // bias chain: 3 matvecs, each parallel over the 128 outputs.
        sh[j] = bv[j];
        __syncthreads();
        float t = biv[j];
        #pragma unroll 16
        for (int k = 0; k < HID; ++k) t += Wiv[j * HID + k] * sh[k];
        __syncthreads(); sh[j] = t; __syncthreads();
        t = b_mo[j];
        #pragma unroll 16
        for (int k = 0; k < HID; ++k) t += W_mo[j * HID + k] * sh[k];
        __syncthreads(); sh[j] = t; __syncthreads();
        t = bo[j];
        #pragma unroll 16
        for (int k = 0; k < HID; ++k) t += Wo[j * HID + k] * sh[k];
        cv[j] = 0.5f * t;
    }
}

// ---------------------------------------------------------------------------
// K2: M' = bf16( I + 0.5 * P_left @ P_right )   (row-major [n][k])
// ---------------------------------------------------------------------------
__global__ void prep_final(const float* __restrict__ Pl,
                           const float* __restrict__ Pr,
                           __hip_bfloat16* __restrict__ Mb)
{
    const int i = blockIdx.x, j = threadIdx.x;
    __shared__ float sh[HID];
    sh[j] = Pl[i * HID + j];
    __syncthreads();
    float s = 0.f;
    #pragma unroll 16
    for (int k = 0; k < HID; ++k) s += sh[k] * Pr[k * HID + j];
    Mb[i * HID + j] = __float2bfloat16(((i == j) ? 1.0f : 0.0f) + 0.5f * s);
}

// ---------------------------------------------------------------------------
// Main: out[e][:] = ea[e][:] @ M'^T + cv      (fp32 in/out, bf16 MFMA)
//
// M' is the A-operand (features = M-dim, in registers), edges are the
// B-operand (N-dim, across lanes). C/D layout gives each lane 4 CONTIGUOUS
// floats of one edge row per acc register -> dwordx4 nontemporal stores.
//
// R2 lesson: __launch_bounds__(256,8) clamped VGPR 60->32 and spilled the
// Mfrag/raw state to scratch (FETCH 63->422 MB, dur 95->228us). Keep the
// natural 60-VGPR allocation (plain launch_bounds(256)): 60 <= 64 already
// permits 8 waves/SIMD. The ONLY change vs the 95us baseline is the grid,
// 1024 -> 2048 blocks (4 -> 8 blocks/CU), which is what the occupancy cap
// actually was.
// ---------------------------------------------------------------------------
__global__ __launch_bounds__(256) void edge_gemm(
    const float* __restrict__ ea,
    const __hip_bfloat16* __restrict__ Mb,   // [128][128] bf16: M'[n][k]
    const float* __restrict__ cvec,          // [128] = 0.5*c
    float* __restrict__ out,
    int E, int numTiles)
{
    const int lane  = threadIdx.x & 63;
    const int wv    = threadIdx.x >> 6;
    const int q     = lane >> 4;      // 0..3
    const int c     = lane & 15;      // 0..15
    const int ncol0 = wv * 32;        // this wave's 32 output cols

    // A-frag: lane (q,c) holds M'[ncol0 + nt*16 + c][kk*32 + q*8 .. +7]
    short8 Mfrag[2][4];
    #pragma unroll
    for (int nt = 0; nt < 2; ++nt) {
        const __hip_bfloat16* mp = Mb + (size_t)(ncol0 + nt * 16 + c) * HID + q * 8;
        #pragma unroll
        for (int kk = 0; kk < 4; ++kk)
            Mfrag[nt][kk] = *reinterpret_cast<const short8*>(mp + kk * 32);
    }
    // Bias as accumulator init: acc[nt][r] <-> out col ncol0 + nt*16 + q*4 + r
    f32x4 cvp[2];
    #pragma unroll
    for (int nt = 0; nt < 2; ++nt)
        cvp[nt] = *reinterpret_cast<const f32x4*>(cvec + ncol0 + nt * 16 + q * 4);

    int t = blockIdx.x;
    if (t >= numTiles) return;

    // Preload tile t's edge data (raw fp32; cast to bf16 when consumed).
    float4 raw[8];
    {
        int row = t * 16 + c; if (row > E - 1) row = E - 1;
        const float* ap = ea + (size_t)row * HID + q * 8;
        #pragma unroll
        for (int kk = 0; kk < 4; ++kk) {
            raw[2 * kk]     = *reinterpret_cast<const float4*>(ap + kk * 32);
            raw[2 * kk + 1] = *reinterpret_cast<const float4*>(ap + kk * 32 + 4);
        }
    }

    while (true) {
        const int edge0 = t * 16;
        const int tn    = t + gridDim.x;

        // B-frag: lane (q,c) holds ea[edge0+c][kk*32 + q*8 .. +7] as bf16.
        short8 bfrag[4];
        #pragma unroll
        for (int kk = 0; kk < 4; ++kk) {
            const float4 f0 = raw[2 * kk], f1 = raw[2 * kk + 1];
            short8 v;
            v[0] = f2bf(f0.x); v[1] = f2bf(f0.y); v[2] = f2bf(f0.z); v[3] = f2bf(f0.w);
            v[4] = f2bf(f1.x); v[5] = f2bf(f1.y); v[6] = f2bf(f1.z); v[7] = f2bf(f1.w);
            bfrag[kk] = v;
        }

        // Software prefetch of tile tn (issued BEFORE this tile's stores).
        if (tn < numTiles) {
            int row = tn * 16 + c; if (row > E - 1) row = E - 1;
            const float* ap = ea + (size_t)row * HID + q * 8;
            #pragma unroll
            for (int kk = 0; kk < 4; ++kk) {
                raw[2 * kk]     = *reinterpret_cast<const float4*>(ap + kk * 32);
                raw[2 * kk + 1] = *reinterpret_cast<const float4*>(ap + kk * 32 + 4);
            }
        }

        f32x4 acc[2] = { cvp[0], cvp[1] };
        #pragma unroll
        for (int kk = 0; kk < 4; ++kk) {
            acc[0] = __builtin_amdgcn_mfma_f32_16x16x32_bf16(Mfrag[0][kk], bfrag[kk], acc[0], 0, 0, 0);
            acc[1] = __builtin_amdgcn_mfma_f32_16x16x32_bf16(Mfrag[1][kk], bfrag[kk], acc[1], 0, 0, 0);
        }

        // acc[nt] = out[edge0+c][ncol0 + nt*16 + q*4 .. +3]  — contiguous.
        const int orow = edge0 + c;
        if (orow < E) {
            float* op = out + (size_t)orow * HID + ncol0 + q * 4;
            __builtin_nontemporal_store(acc[0], reinterpret_cast<f32x4*>(op));
            __builtin_nontemporal_store(acc[1], reinterpret_cast<f32x4*>(op + 16));
        }

        if (tn >= numTiles) break;
        t = tn;
    }
}

// ---------------------------------------------------------------------------
// Inputs (setup_inputs order, all float32; edge_index int64 — DEAD):
//  0 edge_attr  1 node_features(DEAD)  2 regime_probs(DEAD)
//  3 Wq 4 bq 5 Wk 6 bk (DEAD: softmax over singleton seq = 1 => att = v2)
//  7 Wv 8 bv  9 W_in[3*128,128] 10 b_in[384] (only value third live)
// 11 W_mo 12 b_mo 13 Wo 14 bo 15 edge_index(DEAD)
// out = ea @ (I + 0.5*Wo@W_mo@Wiv@Wv)^T + 0.5*c
// ---------------------------------------------------------------------------
extern "C" void kernel_launch(void* const* d_in, const int* in_sizes, int n_in,
                              void* d_out, int out_size, void* d_ws, size_t ws_size,
                              hipStream_t stream) {
    const float* Wv   = (const float*)d_in[7];
    const float* bv   = (const float*)d_in[8];
    const float* W_in = (const float*)d_in[9];
    const float* b_in = (const float*)d_in[10];
    const float* W_mo = (const float*)d_in[11];
    const float* b_mo = (const float*)d_in[12];
    const float* Wo   = (const float*)d_in[13];
    const float* bo   = (const float*)d_in[14];
    const float* Wiv  = W_in + 2 * HID * HID;   // value third of packed in-proj
    const float* biv  = b_in + 2 * HID;

    char* ws = (char*)d_ws;
    float*          Pl = (float*)(ws);                    // 64 KB
    float*          Pr = (float*)(ws + 65536);            // 64 KB
    __hip_bfloat16* Mb = (__hip_bfloat16*)(ws + 131072);  // 32 KB
    float*          cv = (float*)(ws + 163840);           // 512 B

    const int E = in_sizes[0] / HID;
    const int numTiles = (E + 15) / 16;
    const int grid = numTiles < 2048 ? numTiles : 2048;   // 8 blocks/CU resident

    prep_products<<<dim3(257), dim3(HID), 0, stream>>>(
        Wo, W_mo, Wiv, Wv, bv, biv, b_mo, bo, Pl, Pr, cv);
    prep_final<<<dim3(HID), dim3(HID), 0, stream>>>(Pl, Pr, Mb);

    edge_gemm<<<dim3(grid), dim3(256), 0, stream>>>(
        (const float*)d_in[0], Mb, cv, (float*)d_out, E, numTiles);
}

// Round 3
// 283.718 us; speedup vs baseline: 1.4920x; 1.0504x over previous
//
#include <hip/hip_runtime.h>
#include <hip/hip_bf16.h>

#define HID 128

typedef __attribute__((ext_vector_type(8))) short short8;   // 8 x bf16 (4 VGPRs)
typedef __attribute__((ext_vector_type(4))) float f32x4;    // MFMA C/D

static __device__ __forceinline__ short f2bf(float x) {
    __hip_bfloat16 h = __float2bfloat16(x);   // RNE
    return *reinterpret_cast<short*>(&h);
}

// ---------------------------------------------------------------------------
// K1: the two INDEPENDENT 128x128 products in one launch, plus the bias
// chain parallelized over its 128 outputs.
//   blocks 0..127   : P_left  = Wo  @ W_mo      (row b)
//   blocks 128..255 : P_right = Wiv @ Wv        (row b-128)
//   block  256      : cv = 0.5*(Wo@(W_mo@(Wiv@bv + biv) + b_mo) + bo)
// ---------------------------------------------------------------------------
__global__ void prep_products(const float* __restrict__ Wo,
                              const float* __restrict__ W_mo,
                              const float* __restrict__ Wiv,
                              const float* __restrict__ Wv,
                              const float* __restrict__ bv,
                              const float* __restrict__ biv,
                              const float* __restrict__ b_mo,
                              const float* __restrict__ bo,
                              float* __restrict__ Pl,
                              float* __restrict__ Pr,
                              float* __restrict__ cv)
{
    const int j = threadIdx.x;
    const int b = blockIdx.x;
    __shared__ float sh[HID];

    if (b < 256) {
        const float* A = (b < 128) ? Wo   : Wiv;
        const float* B = (b < 128) ? W_mo : Wv;
        float*       C = (b < 128) ? Pl   : Pr;
        const int i = b & 127;
        sh[j] = A[i * HID + j];
        __syncthreads();
        float s = 0.f;
        #pragma unroll 16
        for (int k = 0; k < HID; ++k) s += sh[k] * B[k * HID + j];
        C[i * HID + j] = s;
    } else {
        // bias chain: 3 matvecs, each parallel over the 128 outputs.
        sh[j] = bv[j];
        __syncthreads();
        float t = biv[j];
        #pragma unroll 16
        for (int k = 0; k < HID; ++k) t += Wiv[j * HID + k] * sh[k];
        __syncthreads(); sh[j] = t; __syncthreads();
        t = b_mo[j];
        #pragma unroll 16
        for (int k = 0; k < HID; ++k) t += W_mo[j * HID + k] * sh[k];
        __syncthreads(); sh[j] = t; __syncthreads();
        t = bo[j];
        #pragma unroll 16
        for (int k = 0; k < HID; ++k) t += Wo[j * HID + k] * sh[k];
        cv[j] = 0.5f * t;
    }
}

// ---------------------------------------------------------------------------
// K2: M' = bf16( I + 0.5 * P_left @ P_right )   (row-major [n][k])
// ---------------------------------------------------------------------------
__global__ void prep_final(const float* __restrict__ Pl,
                           const float* __restrict__ Pr,
                           __hip_bfloat16* __restrict__ Mb)
{
    const int i = blockIdx.x, j = threadIdx.x;
    __shared__ float sh[HID];
    sh[j] = Pl[i * HID + j];
    __syncthreads();
    float s = 0.f;
    #pragma unroll 16
    for (int k = 0; k < HID; ++k) s += sh[k] * Pr[k * HID + j];
    Mb[i * HID + j] = __float2bfloat16(((i == j) ? 1.0f : 0.0f) + 0.5f * s);
}

// ---------------------------------------------------------------------------
// Main: out[e][:] = ea[e][:] @ M'^T + cv      (fp32 in/out, bf16 MFMA)
//
// R3 analysis: the old register-direct B loads touched 32 discontiguous
// cachelines PER INSTRUCTION (16 rows x 2 lines, 2 lanes/line), and the 4
// waves loaded the same bytes redundantly: ~1150 L1 transactions per tile.
// Measured 930 cyc/wave-iter with all pipes <7% busy and occupancy-
// insensitivity (R2) == per-CU address-unit saturation.
//
// Fix: stage the 16x512B tile into LDS ONCE per block via 8x
// global_load_lds width-16 (fully contiguous: 16 txns/instr -> 128/tile),
// double-buffered.  Global source is PRE-SWIZZLED (byte ^= (row&7)<<4,
// 16B-granule XOR) so the linear LDS image is bank-swizzled; ds_read_b128
// fragment reads apply the same XOR and are conflict-free (8 lanes per 16B
// chunk position = balanced for b128's 8-phase minimum).  Counted
// s_waitcnt vmcnt(2) + raw s_barrier: next-tile stage stays in flight,
// stores are never drained in-loop.
// ---------------------------------------------------------------------------
__global__ __launch_bounds__(256) void edge_gemm(
    const float* __restrict__ ea,
    const __hip_bfloat16* __restrict__ Mb,   // [128][128] bf16: M'[n][k]
    const float* __restrict__ cvec,          // [128] = 0.5*c
    float* __restrict__ out,
    int E, int numTiles)
{
    __shared__ __align__(16) float lds[2][2048];   // 2 x 16 rows x 512 B

    const int lane  = threadIdx.x & 63;
    const int wv    = threadIdx.x >> 6;
    const int q     = lane >> 4;      // 0..3
    const int c     = lane & 15;      // 0..15
    const int ncol0 = wv * 32;        // this wave's 32 output cols

    // A-frag: lane (q,c) holds M'[ncol0 + nt*16 + c][kk*32 + q*8 .. +7]
    short8 Mfrag[2][4];
    #pragma unroll
    for (int nt = 0; nt < 2; ++nt) {
        const __hip_bfloat16* mp = Mb + (size_t)(ncol0 + nt * 16 + c) * HID + q * 8;
        #pragma unroll
        for (int kk = 0; kk < 4; ++kk)
            Mfrag[nt][kk] = *reinterpret_cast<const short8*>(mp + kk * 32);
    }
    // Bias as accumulator init: acc[nt][r] <-> out col ncol0 + nt*16 + q*4 + r
    f32x4 cvp[2];
    #pragma unroll
    for (int nt = 0; nt < 2; ++nt)
        cvp[nt] = *reinterpret_cast<const f32x4*>(cvec + ncol0 + nt * 16 + q * 4);

    int t = blockIdx.x;
    if (t >= numTiles) return;

    // ds_read addressing: ea[row c][byte kk*128 + q*32 + h*16] lives at LDS
    // byte c*512 + ((kk*128+q*32+h*16) ^ ((c&7)<<4)).  Fields are disjoint:
    // fold the q-part and h-part of the XOR separately.
    const int swz   = (c & 7) << 4;
    const int rbase = c * 512 + ((q * 32) ^ (swz & 0x60));
    const int hx    = swz & 16;

    // Staging lambda: wave wv issues instrs i=2wv,2wv+1; instr i fills LDS
    // bytes [i*1024, i*1024+1024) linearly (HW: uniform base + lane*16).
    // Source byte for linear pos p = i*1024 + lane*16:
    //   r = p>>9 (tile row), b = (p&511) ^ ((r&7)<<4)  (pre-swizzle).
    auto stage_tile = [&](float* ldsbuf, int edge0) {
        #pragma unroll
        for (int j = 0; j < 2; ++j) {
            const int i = wv * 2 + j;
            const int r = i * 2 + (lane >> 5);
            const int b = ((lane & 31) * 16) ^ ((r & 7) << 4);
            int grow = edge0 + r; if (grow > E - 1) grow = E - 1;
            const char* src = (const char*)ea + (size_t)grow * 512 + b;
            float* dst = ldsbuf + i * 256;    // wave-uniform LDS base
            __builtin_amdgcn_global_load_lds(
                (const __attribute__((address_space(1))) void*)src,
                (__attribute__((address_space(3))) void*)dst,
                16, 0, 0);
        }
    };

    // Prologue: stage tile t into buf0, full drain once.
    stage_tile(&lds[0][0], t * 16);
    asm volatile("s_waitcnt vmcnt(0)" ::: "memory");
    __builtin_amdgcn_s_barrier();
    __builtin_amdgcn_sched_barrier(0);

    int cur = 0;
    while (true) {
        const int edge0 = t * 16;
        const int tn    = t + gridDim.x;
        const bool has_next = (tn < numTiles);

        // Issue next tile's stage first: its latency hides under this tile's
        // LDS reads + MFMA + stores.
        if (has_next) stage_tile(&lds[cur ^ 1][0], tn * 16);

        // B-frag from LDS (swizzled), cvt fp32 -> bf16.
        const char* lb = (const char*)&lds[cur][0];
        short8 bfrag[4];
        #pragma unroll
        for (int kk = 0; kk < 4; ++kk) {
            const float4 f0 = *reinterpret_cast<const float4*>(lb + rbase + kk * 128 + hx);
            const float4 f1 = *reinterpret_cast<const float4*>(lb + rbase + kk * 128 + (16 ^ hx));
            short8 v;
            v[0] = f2bf(f0.x); v[1] = f2bf(f0.y); v[2] = f2bf(f0.z); v[3] = f2bf(f0.w);
            v[4] = f2bf(f1.x); v[5] = f2bf(f1.y); v[6] = f2bf(f1.z); v[7] = f2bf(f1.w);
            bfrag[kk] = v;
        }

        f32x4 acc[2] = { cvp[0], cvp[1] };
        #pragma unroll
        for (int kk = 0; kk < 4; ++kk) {
            acc[0] = __builtin_amdgcn_mfma_f32_16x16x32_bf16(Mfrag[0][kk], bfrag[kk], acc[0], 0, 0, 0);
            acc[1] = __builtin_amdgcn_mfma_f32_16x16x32_bf16(Mfrag[1][kk], bfrag[kk], acc[1], 0, 0, 0);
        }

        // acc[nt] = out[edge0+c][ncol0 + nt*16 + q*4 .. +3]  — contiguous.
        const int orow = edge0 + c;
        if (orow < E) {
            float* op = out + (size_t)orow * HID + ncol0 + q * 4;
            __builtin_nontemporal_store(acc[0], reinterpret_cast<f32x4*>(op));
            __builtin_nontemporal_store(acc[1], reinterpret_cast<f32x4*>(op + 16));
        }

        if (!has_next) break;

        // Wait for THIS wave's 2 stage ops (oldest in queue; the 2 stores may
        // stay in flight), then block-wide barrier: buf[cur^1] fully staged
        // and everyone is done reading buf[cur].
        asm volatile("s_waitcnt vmcnt(2)" ::: "memory");
        __builtin_amdgcn_s_barrier();
        __builtin_amdgcn_sched_barrier(0);

        cur ^= 1;
        t = tn;
    }
}

// ---------------------------------------------------------------------------
// Inputs (setup_inputs order, all float32; edge_index int64 — DEAD):
//  0 edge_attr  1 node_features(DEAD)  2 regime_probs(DEAD)
//  3 Wq 4 bq 5 Wk 6 bk (DEAD: softmax over singleton seq = 1 => att = v2)
//  7 Wv 8 bv  9 W_in[3*128,128] 10 b_in[384] (only value third live)
// 11 W_mo 12 b_mo 13 Wo 14 bo 15 edge_index(DEAD)
// out = ea @ (I + 0.5*Wo@W_mo@Wiv@Wv)^T + 0.5*c
// ---------------------------------------------------------------------------
extern "C" void kernel_launch(void* const* d_in, const int* in_sizes, int n_in,
                              void* d_out, int out_size, void* d_ws, size_t ws_size,
                              hipStream_t stream) {
    const float* Wv   = (const float*)d_in[7];
    const float* bv   = (const float*)d_in[8];
    const float* W_in = (const float*)d_in[9];
    const float* b_in = (const float*)d_in[10];
    const float* W_mo = (const float*)d_in[11];
    const float* b_mo = (const float*)d_in[12];
    const float* Wo   = (const float*)d_in[13];
    const float* bo   = (const float*)d_in[14];
    const float* Wiv  = W_in + 2 * HID * HID;   // value third of packed in-proj
    const float* biv  = b_in + 2 * HID;

    char* ws = (char*)d_ws;
    float*          Pl = (float*)(ws);                    // 64 KB
    float*          Pr = (float*)(ws + 65536);            // 64 KB
    __hip_bfloat16* Mb = (__hip_bfloat16*)(ws + 131072);  // 32 KB
    float*          cv = (float*)(ws + 163840);           // 512 B

    const int E = in_sizes[0] / HID;
    const int numTiles = (E + 15) / 16;
    const int grid = numTiles < 2048 ? numTiles : 2048;

    prep_products<<<dim3(257), dim3(HID), 0, stream>>>(
        Wo, W_mo, Wiv, Wv, bv, biv, b_mo, bo, Pl, Pr, cv);
    prep_final<<<dim3(HID), dim3(HID), 0, stream>>>(Pl, Pr, Mb);

    edge_gemm<<<dim3(grid), dim3(256), 0, stream>>>(
        (const float*)d_in[0], Mb, cv, (float*)d_out, E, numTiles);
}

// Round 5
// 281.084 us; speedup vs baseline: 1.5060x; 1.0094x over previous
//
#include <hip/hip_runtime.h>
#include <hip/hip_bf16.h>

#define HID 128

typedef __attribute__((ext_vector_type(8))) short short8;   // 8 x bf16 (4 VGPRs)
typedef __attribute__((ext_vector_type(4))) float f32x4;    // MFMA C/D

static __device__ __forceinline__ short f2bf(float x) {
    __hip_bfloat16 h = __float2bfloat16(x);   // RNE
    return *reinterpret_cast<short*>(&h);
}

// ---------------------------------------------------------------------------
// K1: the two INDEPENDENT 128x128 products in one launch, plus the bias
// chain parallelized over its 128 outputs.
//   blocks 0..127   : P_left  = Wo  @ W_mo      (row b)
//   blocks 128..255 : P_right = Wiv @ Wv        (row b-128)
//   block  256      : cv = 0.5*(Wo@(W_mo@(Wiv@bv + biv) + b_mo) + bo)
// ---------------------------------------------------------------------------
__global__ void prep_products(const float* __restrict__ Wo,
                              const float* __restrict__ W_mo,
                              const float* __restrict__ Wiv,
                              const float* __restrict__ Wv,
                              const float* __restrict__ bv,
                              const float* __restrict__ biv,
                              const float* __restrict__ b_mo,
                              const float* __restrict__ bo,
                              float* __restrict__ Pl,
                              float* __restrict__ Pr,
                              float* __restrict__ cv)
{
    const int j = threadIdx.x;
    const int b = blockIdx.x;
    __shared__ float sh[HID];

    if (b < 256) {
        const float* A = (b < 128) ? Wo   : Wiv;
        const float* B = (b < 128) ? W_mo : Wv;
        float*       C = (b < 128) ? Pl   : Pr;
        const int i = b & 127;
        sh[j] = A[i * HID + j];
        __syncthreads();
        float s = 0.f;
        #pragma unroll 16
        for (int k = 0; k < HID; ++k) s += sh[k] * B[k * HID + j];
        C[i * HID + j] = s;
    } else {
        // bias chain: 3 matvecs, each parallel over the 128 outputs.
        sh[j] = bv[j];
        __syncthreads();
        float t = biv[j];
        #pragma unroll 16
        for (int k = 0; k < HID; ++k) t += Wiv[j * HID + k] * sh[k];
        __syncthreads(); sh[j] = t; __syncthreads();
        t = b_mo[j];
        #pragma unroll 16
        for (int k = 0; k < HID; ++k) t += W_mo[j * HID + k] * sh[k];
        __syncthreads(); sh[j] = t; __syncthreads();
        t = bo[j];
        #pragma unroll 16
        for (int k = 0; k < HID; ++k) t += Wo[j * HID + k] * sh[k];
        cv[j] = 0.5f * t;
    }
}

// ---------------------------------------------------------------------------
// K2: M' = bf16( I + 0.5 * P_left @ P_right )   (row-major [n][k])
// ---------------------------------------------------------------------------
__global__ void prep_final(const float* __restrict__ Pl,
                           const float* __restrict__ Pr,
                           __hip_bfloat16* __restrict__ Mb)
{
    const int i = blockIdx.x, j = threadIdx.x;
    __shared__ float sh[HID];
    sh[j] = Pl[i * HID + j];
    __syncthreads();
    float s = 0.f;
    #pragma unroll 16
    for (int k = 0; k < HID; ++k) s += sh[k] * Pr[k * HID + j];
    Mb[i * HID + j] = __float2bfloat16(((i == j) ? 1.0f : 0.0f) + 0.5f * s);
}

// ---------------------------------------------------------------------------
// Main: out[e][:] = ea[e][:] @ M'^T + cv      (fp32 in/out, bf16 MFMA)
//
// R4/R5: R3 (LDS staging, depth-2, nontemporal stores) was still
// latency-serialized at ~3.2K cyc/tile with all pipes <8% busy:
//  (a) depth-2 means the vmcnt wait targets a stage issued ~400 cy earlier
//      vs ~1-1.5K cy loaded HBM latency -> near-full latency per iteration;
//  (b) vmcnt retires IN ORDER, so waiting for stage_{j+1} transitively
//      waits for iter j-1's NONTEMPORAL stores to commit at HBM (nt
//      bypasses L2 -> slow ack). Every iteration chained behind write acks.
// Fix: plain stores (L2 ack, full-line writes so no RFO) + DEPTH-3 staging
// (3 x 8KB LDS): buffer read at iter j was staged at iter j-2, so the
// vmcnt(4) wait target completed ~one full iteration earlier. Steady state
// stalls only on issue, not memory latency.
// (R4 bench was an infra failure — container acquire; kernel re-audited for
// barrier uniformity / vmcnt tail behavior / OOB, resubmitted unchanged.)
// ---------------------------------------------------------------------------
__global__ __launch_bounds__(256) void edge_gemm(
    const float* __restrict__ ea,
    const __hip_bfloat16* __restrict__ Mb,   // [128][128] bf16: M'[n][k]
    const float* __restrict__ cvec,          // [128] = 0.5*c
    float* __restrict__ out,
    int E, int numTiles)
{
    __shared__ __align__(16) float lds[3][2048];   // 3 x 16 rows x 512 B

    const int lane  = threadIdx.x & 63;
    const int wv    = threadIdx.x >> 6;
    const int q     = lane >> 4;      // 0..3
    const int c     = lane & 15;      // 0..15
    const int ncol0 = wv * 32;        // this wave's 32 output cols

    // A-frag: lane (q,c) holds M'[ncol0 + nt*16 + c][kk*32 + q*8 .. +7]
    short8 Mfrag[2][4];
    #pragma unroll
    for (int nt = 0; nt < 2; ++nt) {
        const __hip_bfloat16* mp = Mb + (size_t)(ncol0 + nt * 16 + c) * HID + q * 8;
        #pragma unroll
        for (int kk = 0; kk < 4; ++kk)
            Mfrag[nt][kk] = *reinterpret_cast<const short8*>(mp + kk * 32);
    }
    // Bias as accumulator init: acc[nt][r] <-> out col ncol0 + nt*16 + q*4 + r
    f32x4 cvp[2];
    #pragma unroll
    for (int nt = 0; nt < 2; ++nt)
        cvp[nt] = *reinterpret_cast<const f32x4*>(cvec + ncol0 + nt * 16 + q * 4);

    int t = blockIdx.x;
    if (t >= numTiles) return;
    const int G = gridDim.x;

    // ds_read addressing: ea[row c][byte kk*128 + q*32 + h*16] lives at LDS
    // byte c*512 + ((kk*128+q*32+h*16) ^ ((c&7)<<4)).  Fields are disjoint:
    // fold the q-part and h-part of the XOR separately.
    const int swz   = (c & 7) << 4;
    const int rbase = c * 512 + ((q * 32) ^ (swz & 0x60));
    const int hx    = swz & 16;

    // Staging: wave wv issues instrs i=2wv,2wv+1; instr i fills LDS bytes
    // [i*1024, i*1024+1024) linearly (HW: uniform base + lane*16).
    // Source byte for linear pos p = i*1024 + lane*16:
    //   r = p>>9 (tile row), b = (p&511) ^ ((r&7)<<4)  (pre-swizzle).
    auto stage_tile = [&](float* ldsbuf, int edge0) {
        #pragma unroll
        for (int j = 0; j < 2; ++j) {
            const int i = wv * 2 + j;
            const int r = i * 2 + (lane >> 5);
            const int b = ((lane & 31) * 16) ^ ((r & 7) << 4);
            int grow = edge0 + r; if (grow > E - 1) grow = E - 1;
            const char* src = (const char*)ea + (size_t)grow * 512 + b;
            float* dst = ldsbuf + i * 256;    // wave-uniform LDS base
            __builtin_amdgcn_global_load_lds(
                (const __attribute__((address_space(1))) void*)src,
                (__attribute__((address_space(3))) void*)dst,
                16, 0, 0);
        }
    };

    // Prologue: stage tiles t and t+G, full drain once.
    stage_tile(&lds[0][0], t * 16);
    if (t + G < numTiles) stage_tile(&lds[1][0], (t + G) * 16);
    asm volatile("s_waitcnt vmcnt(0)" ::: "memory");
    __builtin_amdgcn_s_barrier();
    __builtin_amdgcn_sched_barrier(0);

    int cur = 0;
    while (true) {
        const int edge0 = t * 16;
        const bool has_next  = (t + G     < numTiles);
        const bool has_next2 = (t + 2 * G < numTiles);

        // Stage tile t+2G into buffer cur-1 (the one read LAST iteration;
        // the barrier at the end of that iteration made it free).
        if (has_next2) {
            int nb = cur + 2; if (nb >= 3) nb -= 3;
            stage_tile(&lds[nb][0], (t + 2 * G) * 16);
        }

        // B-frag from LDS (swizzled), cvt fp32 -> bf16.
        const char* lb = (const char*)&lds[cur][0];
        short8 bfrag[4];
        #pragma unroll
        for (int kk = 0; kk < 4; ++kk) {
            const float4 f0 = *reinterpret_cast<const float4*>(lb + rbase + kk * 128 + hx);
            const float4 f1 = *reinterpret_cast<const float4*>(lb + rbase + kk * 128 + (16 ^ hx));
            short8 v;
            v[0] = f2bf(f0.x); v[1] = f2bf(f0.y); v[2] = f2bf(f0.z); v[3] = f2bf(f0.w);
            v[4] = f2bf(f1.x); v[5] = f2bf(f1.y); v[6] = f2bf(f1.z); v[7] = f2bf(f1.w);
            bfrag[kk] = v;
        }

        f32x4 acc[2] = { cvp[0], cvp[1] };
        #pragma unroll
        for (int kk = 0; kk < 4; ++kk) {
            acc[0] = __builtin_amdgcn_mfma_f32_16x16x32_bf16(Mfrag[0][kk], bfrag[kk], acc[0], 0, 0, 0);
            acc[1] = __builtin_amdgcn_mfma_f32_16x16x32_bf16(Mfrag[1][kk], bfrag[kk], acc[1], 0, 0, 0);
        }

        // acc[nt] = out[edge0+c][ncol0 + nt*16 + q*4 .. +3]  — contiguous,
        // PLAIN stores (L2 write-back ack; full 64B lines per 4 lanes).
        const int orow = edge0 + c;
        if (orow < E) {
            float* op = out + (size_t)orow * HID + ncol0 + q * 4;
            *reinterpret_cast<f32x4*>(op)      = acc[0];
            *reinterpret_cast<f32x4*>(op + 16) = acc[1];
        }

        if (!has_next) break;

        // vmcnt(4): retires (at least) the stage issued LAST iteration for
        // the buffer read NEXT iteration, plus last iter's stores (cheap L2
        // acks). This iter's stage(2) + stores(2) may stay in flight.
        asm volatile("s_waitcnt vmcnt(4)" ::: "memory");
        __builtin_amdgcn_s_barrier();
        __builtin_amdgcn_sched_barrier(0);

        cur += 1; if (cur >= 3) cur -= 3;
        t += G;
    }
}

// ---------------------------------------------------------------------------
// Inputs (setup_inputs order, all float32; edge_index int64 — DEAD):
//  0 edge_attr  1 node_features(DEAD)  2 regime_probs(DEAD)
//  3 Wq 4 bq 5 Wk 6 bk (DEAD: softmax over singleton seq = 1 => att = v2)
//  7 Wv 8 bv  9 W_in[3*128,128] 10 b_in[384] (only value third live)
// 11 W_mo 12 b_mo 13 Wo 14 bo 15 edge_index(DEAD)
// out = ea @ (I + 0.5*Wo@W_mo@Wiv@Wv)^T + 0.5*c
// ---------------------------------------------------------------------------
extern "C" void kernel_launch(void* const* d_in, const int* in_sizes, int n_in,
                              void* d_out, int out_size, void* d_ws, size_t ws_size,
                              hipStream_t stream) {
    const float* Wv   = (const float*)d_in[7];
    const float* bv   = (const float*)d_in[8];
    const float* W_in = (const float*)d_in[9];
    const float* b_in = (const float*)d_in[10];
    const float* W_mo = (const float*)d_in[11];
    const float* b_mo = (const float*)d_in[12];
    const float* Wo   = (const float*)d_in[13];
    const float* bo   = (const float*)d_in[14];
    const float* Wiv  = W_in + 2 * HID * HID;   // value third of packed in-proj
    const float* biv  = b_in + 2 * HID;

    char* ws = (char*)d_ws;
    float*          Pl = (float*)(ws);                    // 64 KB
    float*          Pr = (float*)(ws + 65536);            // 64 KB
    __hip_bfloat16* Mb = (__hip_bfloat16*)(ws + 131072);  // 32 KB
    float*          cv = (float*)(ws + 163840);           // 512 B

    const int E = in_sizes[0] / HID;
    const int numTiles = (E + 15) / 16;
    const int grid = numTiles < 2048 ? numTiles : 2048;

    prep_products<<<dim3(257), dim3(HID), 0, stream>>>(
        Wo, W_mo, Wiv, Wv, bv, biv, b_mo, bo, Pl, Pr, cv);
    prep_final<<<dim3(HID), dim3(HID), 0, stream>>>(Pl, Pr, Mb);

    edge_gemm<<<dim3(grid), dim3(256), 0, stream>>>(
        (const float*)d_in[0], Mb, cv, (float*)d_out, E, numTiles);
}